// Round 3
// baseline (37697.421 us; speedup 1.0000x reference)
//
#include <hip/hip_runtime.h>
#include <math.h>

#define TSTEPS 1024
#define BB 256
#define HH 256
#define INPUT 16
#define HBUF (BB*HH)

// ---- workspace layout (float offsets) ----
// Read-only after prep (via `wro`):
//   Wg1s  [256 j][128 kq][4 gate][4 ki]   (k = concat(h0 k<256, h1 k>=256))
//   Wg0hs [256 j][ 64 kq][4][4]
//   Wg0xs [256 j][  4 kq][4][4]
//   bs0/bs1 [256 j][4 gate]
// Mutable state (via `hrw`):
//   h0T/h1T [2 buf][256 j][256 r]  (TRANSPOSED: coalesced cell writes + clean LDS staging)
//   c0T/c1T [256 j][256 r]
//   pbuf [2][8 jb][256 r]
#define OFF_WG1S  0u
#define OFF_WG0HS 524288u
#define OFF_WG0XS 786432u
#define OFF_BS0   802816u
#define OFF_BS1   803840u
#define OFF_H0    804864u
#define OFF_H1    935936u
#define OFF_C0T   1067008u
#define OFF_C1T   1132544u
#define OFF_PB    1198080u
#define WS_FLOATS 1202176u

__device__ __forceinline__ float fast_sigmoid(float v) {
    return __builtin_amdgcn_rcpf(1.0f + __expf(-v));
}
__device__ __forceinline__ float fast_tanh(float v) {
    return 1.0f - 2.0f * __builtin_amdgcn_rcpf(1.0f + __expf(2.0f * v));
}

__global__ __launch_bounds__(256) void prep_kernel(
    const float* __restrict__ Wih0, const float* __restrict__ Whh0,
    const float* __restrict__ bih0, const float* __restrict__ bhh0,
    const float* __restrict__ Wih1, const float* __restrict__ Whh1,
    const float* __restrict__ bih1, const float* __restrict__ bhh1,
    float* __restrict__ ws)
{
    for (unsigned idx = blockIdx.x * blockDim.x + threadIdx.x; idx < 804864u;
         idx += gridDim.x * blockDim.x) {
        if (idx < 524288u) {                       // Wg1s
            unsigned j = idx >> 11, rem = idx & 2047u;
            unsigned kq = rem >> 4, g = (rem >> 2) & 3u, ki = rem & 3u;
            unsigned k = kq * 4 + ki, row = g * 256 + j;
            ws[idx] = (k < 256u) ? Wih1[row * 256 + k] : Whh1[row * 256 + (k - 256u)];
        } else if (idx < 786432u) {                // Wg0hs
            unsigned i2 = idx - 524288u;
            unsigned j = i2 >> 10, rem = i2 & 1023u;
            unsigned kq = rem >> 4, g = (rem >> 2) & 3u, ki = rem & 3u;
            unsigned k = kq * 4 + ki, row = g * 256 + j;
            ws[idx] = Whh0[row * 256 + k];
        } else if (idx < 802816u) {                // Wg0xs
            unsigned i2 = idx - 786432u;
            unsigned j = i2 >> 6, rem = i2 & 63u;
            unsigned kq = rem >> 4, g = (rem >> 2) & 3u, ki = rem & 3u;
            unsigned k = kq * 4 + ki, row = g * 256 + j;
            ws[idx] = Wih0[row * 16 + k];
        } else if (idx < 803840u) {                // bs0
            unsigned i2 = idx - 802816u;
            unsigned j = i2 >> 2, g = i2 & 3u, row = g * 256 + j;
            ws[idx] = bih0[row] + bhh0[row];
        } else {                                   // bs1
            unsigned i2 = idx - 803840u;
            unsigned j = i2 >> 2, g = i2 & 3u, row = g * 256 + j;
            ws[idx] = bih1[row] + bhh1[row];
        }
    }
}

__global__ __launch_bounds__(256) void zero_state(float* __restrict__ ws) {
    const unsigned n = WS_FLOATS - OFF_H0;
    for (unsigned i = blockIdx.x * blockDim.x + threadIdx.x; i < n;
         i += gridDim.x * blockDim.x)
        ws[OFF_H0 + i] = 0.0f;
}

// Block order chosen for XCD-round-robin balance: blocks 0..255 land one per
// CU; blocks 256..288 (all L0, ~0.5M MAC) land as 2nd block on the CUs that
// hold blocks 0..31 = FC-A (~0.5M MAC) -> max ~1.05M MAC per CU everywhere.
//   blocks [0,32)    : FC-A fc1+relu+fc2 partials, step t-2
//   blocks [32,160)  : layer-1 LSTM cell, step t-1   (64r x 8j x K512)
//   blocks [160,288) : layer-0 LSTM cell, step t     (64r x 8j x K256)
//   block  288       : FC-B final fc2 reduce, step t-3
__global__ __launch_bounds__(256, 2) void lstm_step(
    const float* __restrict__ x,
    const float* __restrict__ fc1w, const float* __restrict__ fc1b,
    const float* __restrict__ fc2w, const float* __restrict__ fc2b,
    const float* __restrict__ wro, float* __restrict__ hrw,
    float* __restrict__ out, int t)
{
    // transposed chunk tiles: [128 k][68 r-slots], double buffered (68 KiB)
    __shared__ __align__(16) float buf[2][128 * 68];
    const int tid  = threadIdx.x;
    const int lane = tid & 63;
    const int wv   = __builtin_amdgcn_readfirstlane(tid >> 6);
    const int blk  = blockIdx.x;

    float* h0 = hrw + OFF_H0;
    float* h1 = hrw + OFF_H1;

    if (blk >= 32 && blk < 288) {
        // ---------------- LSTM roles ----------------
        const bool isL1 = (blk < 160);
        const int  s    = isL1 ? (t - 1) : t;
        if (s < 0 || s >= TSTEPS) return;
        const int bb = isL1 ? (blk - 32) : (blk - 160);
        const int rb = bb >> 5;               // 0..3
        const int jb = bb & 31;               // 0..31
        const int r0 = rb * 64;
        const int j0 = jb * 8 + wv * 2;       // wave's two j columns (uniform)
        const int ra = r0 + lane;

        const float* Wg  = wro + (isL1 ? OFF_WG1S : OFF_WG0HS);
        const float* bs  = wro + (isL1 ? OFF_BS1 : OFF_BS0);
        const float* srcA = isL1 ? (h0 + (s & 1) * HBUF)
                                 : (h0 + ((s + 1) & 1) * HBUF);
        const float* srcB = h1 + ((s + 1) & 1) * HBUF;   // h1(s-1), L1 only
        float* hw = isL1 ? (h1 + (s & 1) * HBUF)
                         : (h0 + (s & 1) * HBUF);
        float* cT = hrw + (isL1 ? OFF_C1T : OFF_C0T);

        const int wstride = isL1 ? 2048 : 1024;
        const int nchunk  = isL1 ? 4 : 2;

        float acc0[4] = {0.f, 0.f, 0.f, 0.f};
        float acc1[4] = {0.f, 0.f, 0.f, 0.f};
        float4 st[8];

        // stage 128-k chunk: global hT[k][r] -> regs -> LDS [k][68]
        auto stage_ld = [&](int c) {
            const float* src; int kb;
            if (isL1 && c >= 2) { src = srcB; kb = (c - 2) * 128; }
            else                { src = srcA; kb = c * 128; }
            #pragma unroll
            for (int i = 0; i < 8; ++i) {
                int f = tid + i * 256;
                int k = f >> 4, rq = f & 15;
                st[i] = *(const float4*)(src + (size_t)(kb + k) * BB + r0 + rq * 4);
            }
        };
        auto stage_st = [&](float* b) {
            #pragma unroll
            for (int i = 0; i < 8; ++i) {
                int f = tid + i * 256;
                int k = f >> 4, rq = f & 15;
                *(float4*)&b[k * 68 + rq * 4] = st[i];
            }
        };

        stage_ld(0);

        // ---- L0 input projection (K=16, per-lane direct global reads) ----
        if (!isL1) {
            const float* xr = x + (size_t)ra * (TSTEPS * INPUT) + (size_t)s * INPUT;
            float4 xv[4];
            #pragma unroll
            for (int q = 0; q < 4; ++q) xv[q] = *(const float4*)(xr + q * 4);
            const float* w0 = wro + OFF_WG0XS;
            #pragma unroll
            for (int q = 0; q < 4; ++q) {
                const float* wj0 = w0 + (size_t)j0 * 64 + q * 16;   // uniform
                const float* wj1 = wj0 + 64;
                float hv[4] = {xv[q].x, xv[q].y, xv[q].z, xv[q].w};
                #pragma unroll
                for (int g = 0; g < 4; ++g) {
                    #pragma unroll
                    for (int m = 0; m < 4; ++m) {
                        acc0[g] = fmaf(hv[m], wj0[g * 4 + m], acc0[g]);
                        acc1[g] = fmaf(hv[m], wj1[g * 4 + m], acc1[g]);
                    }
                }
            }
        }

        stage_st(buf[0]);

        for (int c = 0; c < nchunk; ++c) {
            __syncthreads();
            if (c + 1 < nchunk) { stage_ld(c + 1); stage_st(buf[(c + 1) & 1]); }
            const float* hb = buf[c & 1];
            const float* wbase0 = Wg + (size_t)j0 * wstride + (size_t)c * 512; // c*32 kq *16
            const float* wbase1 = wbase0 + wstride;
            #pragma unroll 8
            for (int kk = 0; kk < 32; ++kk) {
                float hv[4];
                #pragma unroll
                for (int m = 0; m < 4; ++m)
                    hv[m] = hb[(kk * 4 + m) * 68 + lane];   // bank-rotated, conflict-free
                const float* wj0 = wbase0 + kk * 16;         // uniform -> s_load
                const float* wj1 = wbase1 + kk * 16;
                #pragma unroll
                for (int g = 0; g < 4; ++g) {
                    #pragma unroll
                    for (int m = 0; m < 4; ++m) {
                        acc0[g] = fmaf(hv[m], wj0[g * 4 + m], acc0[g]);
                        acc1[g] = fmaf(hv[m], wj1[g * 4 + m], acc1[g]);
                    }
                }
            }
        }

        // ---- cell update (gate order i,f,g,o) ----
        #pragma unroll
        for (int jj = 0; jj < 2; ++jj) {
            const int j = j0 + jj;
            float* acc = jj ? acc1 : acc0;
            float ig = fast_sigmoid(acc[0] + bs[j * 4 + 0]);
            float fg = fast_sigmoid(acc[1] + bs[j * 4 + 1]);
            float gg = fast_tanh   (acc[2] + bs[j * 4 + 2]);
            float og = fast_sigmoid(acc[3] + bs[j * 4 + 3]);
            float cp = cT[j * BB + ra];
            float cn = fg * cp + ig * gg;
            cT[j * BB + ra] = cn;
            hw[(size_t)j * BB + ra] = og * fast_tanh(cn);   // coalesced (transposed h)
        }
    } else if (blk < 32) {
        // ---------------- FC-A: fc1 + relu + fc2 partials for step t-2 ----------------
        const int tt = t - 2;
        if (tt < 0 || tt >= TSTEPS) return;
        const int rb = blk >> 3, jb = blk & 7;
        const int r0 = rb * 64;
        const int j0 = jb * 32 + wv * 8;      // uniform
        const float* hs = h1 + (tt & 1) * HBUF;   // transposed [j][r]

        float acc[8] = {0.f, 0.f, 0.f, 0.f, 0.f, 0.f, 0.f, 0.f};
        float4 st[8];

        auto ld = [&](int c) {
            #pragma unroll
            for (int i = 0; i < 8; ++i) {
                int f = tid + i * 256;
                int k = f >> 4, rq = f & 15;
                st[i] = *(const float4*)(hs + (size_t)(c * 128 + k) * BB + r0 + rq * 4);
            }
        };
        auto sst = [&](float* b) {
            #pragma unroll
            for (int i = 0; i < 8; ++i) {
                int f = tid + i * 256;
                int k = f >> 4, rq = f & 15;
                *(float4*)&b[k * 68 + rq * 4] = st[i];
            }
        };

        ld(0); sst(buf[0]);
        for (int c = 0; c < 2; ++c) {
            __syncthreads();
            if (c == 0) { ld(1); sst(buf[1]); }
            const float* hb = buf[c];
            const int kqb = c * 32;
            #pragma unroll 8
            for (int kk = 0; kk < 32; ++kk) {
                float hv[4];
                #pragma unroll
                for (int m = 0; m < 4; ++m)
                    hv[m] = hb[(kk * 4 + m) * 68 + lane];
                #pragma unroll
                for (int jj = 0; jj < 8; ++jj) {
                    const float* wj = fc1w + (size_t)(j0 + jj) * HH + (kqb + kk) * 4;
                    #pragma unroll
                    for (int m = 0; m < 4; ++m)
                        acc[jj] = fmaf(hv[m], wj[m], acc[jj]);
                }
            }
        }
        float p = 0.f;
        #pragma unroll
        for (int jj = 0; jj < 8; ++jj) {
            const int j = j0 + jj;
            float v = acc[jj] + fc1b[j];
            v = v > 0.f ? v : 0.f;
            p = fmaf(fc2w[j], v, p);
        }
        __syncthreads();
        buf[0][wv * 64 + lane] = p;
        __syncthreads();
        if (tid < 64) {
            float s4 = buf[0][tid] + buf[0][64 + tid] + buf[0][128 + tid] + buf[0][192 + tid];
            hrw[OFF_PB + (unsigned)(t & 1) * 2048u + (unsigned)jb * 256u + r0 + tid] = s4;
        }
    } else {
        // ---------------- FC-B: final fc2 reduce for step t-3 ----------------
        const int tt = t - 3;
        if (tt < 0 || tt >= TSTEPS) return;
        const float* pb = hrw + OFF_PB + (unsigned)((t - 1) & 1) * 2048u;
        float s = fc2b[0];
        #pragma unroll
        for (int jb = 0; jb < 8; ++jb) s += pb[jb * 256 + tid];
        out[(size_t)tid * TSTEPS + tt] = s;
    }
}

extern "C" void kernel_launch(void* const* d_in, const int* in_sizes, int n_in,
                              void* d_out, int out_size, void* d_ws, size_t ws_size,
                              hipStream_t stream)
{
    const float* x    = (const float*)d_in[0];
    const float* Wih0 = (const float*)d_in[1];
    const float* Whh0 = (const float*)d_in[2];
    const float* bih0 = (const float*)d_in[3];
    const float* bhh0 = (const float*)d_in[4];
    const float* Wih1 = (const float*)d_in[5];
    const float* Whh1 = (const float*)d_in[6];
    const float* bih1 = (const float*)d_in[7];
    const float* bhh1 = (const float*)d_in[8];
    const float* fc1w = (const float*)d_in[9];
    const float* fc1b = (const float*)d_in[10];
    const float* fc2w = (const float*)d_in[11];
    const float* fc2b = (const float*)d_in[12];
    float* ws  = (float*)d_ws;
    float* out = (float*)d_out;

    prep_kernel<<<512, 256, 0, stream>>>(Wih0, Whh0, bih0, bhh0,
                                         Wih1, Whh1, bih1, bhh1, ws);
    zero_state<<<512, 256, 0, stream>>>(ws);

    for (int t = 0; t < TSTEPS + 3; ++t)
        lstm_step<<<289, 256, 0, stream>>>(x, fc1w, fc1b, fc2w, fc2b,
                                           ws, ws, out, t);
}